// Round 1
// baseline (540.981 us; speedup 1.0000x reference)
//
#include <hip/hip_runtime.h>

typedef unsigned short ushort_t;
typedef __attribute__((ext_vector_type(8))) short short8;
typedef __attribute__((ext_vector_type(4))) float floatx4;

#define B_ 2
#define S_ 2048
#define D_ 1024
#define NH_ 16
#define HD_ 64
#define M_ 4096

__device__ __forceinline__ ushort_t f2bf(float f) {
    unsigned u = __builtin_bit_cast(unsigned, f);
    return (ushort_t)((u + 0x7FFFu + ((u >> 16) & 1u)) >> 16);
}

// ---------------------------------------------------------------- transpose
__device__ __forceinline__ ushort_t to_bf_elem(float f) { return f2bf(f); }
__device__ __forceinline__ ushort_t to_bf_elem(ushort_t u) { return u; }

template <typename T>
__global__ __launch_bounds__(256) void transpose_to_bf16(
    const T* __restrict__ src, ushort_t* __restrict__ dst,
    int R, int C, long sbatch, long dbatch, int srs, int drs) {
    __shared__ ushort_t tile[32][33];
    src += (size_t)blockIdx.z * sbatch;
    dst += (size_t)blockIdx.z * dbatch;
    int c = blockIdx.x * 32 + threadIdx.x;
    #pragma unroll
    for (int i = 0; i < 4; ++i) {
        int r = blockIdx.y * 32 + threadIdx.y + i * 8;
        if (r < R && c < C) tile[threadIdx.y + i * 8][threadIdx.x] = to_bf_elem(src[(size_t)r * srs + c]);
    }
    __syncthreads();
    int rr = blockIdx.y * 32 + threadIdx.x;
    #pragma unroll
    for (int i = 0; i < 4; ++i) {
        int cc = blockIdx.x * 32 + threadIdx.y + i * 8;
        if (cc < C && rr < R) dst[(size_t)cc * drs + rr] = tile[threadIdx.x][threadIdx.y + i * 8];
    }
}

// ---------------------------------------------------------------- w_sum = sum over (n,h) of W_out[n,h,d]
__global__ __launch_bounds__(256) void wsum_kernel(const float* __restrict__ W_out,
                                                   float* __restrict__ wsum) {
    int col = blockIdx.x * 32 + (threadIdx.x & 31);
    int rg = threadIdx.x >> 5;
    float s = 0.f;
    for (int r = rg; r < NH_ * HD_; r += 8) s += W_out[(size_t)r * D_ + col];
    __shared__ float part[256];
    part[threadIdx.x] = s;
    __syncthreads();
    if (threadIdx.x < 32) {
        float t = 0.f;
        #pragma unroll
        for (int g = 0; g < 8; ++g) t += part[g * 32 + threadIdx.x];
        wsum[blockIdx.x * 32 + threadIdx.x] = t;
    }
}

// ---------------------------------------------------------------- LayerNorm (ddof=1, eps=1e-4) -> bf16
__global__ __launch_bounds__(256) void ln1_kernel(const float* __restrict__ x,
                                                  const float* __restrict__ w,
                                                  const float* __restrict__ b,
                                                  ushort_t* __restrict__ out) {
    int row = blockIdx.x, tid = threadIdx.x;
    float v[4], s = 0.f, ss = 0.f;
    #pragma unroll
    for (int i = 0; i < 4; ++i) {
        v[i] = x[(size_t)row * D_ + tid + i * 256];
        s += v[i]; ss += v[i] * v[i];
    }
    #pragma unroll
    for (int off = 32; off >= 1; off >>= 1) { s += __shfl_xor(s, off); ss += __shfl_xor(ss, off); }
    __shared__ float red[8];
    if ((tid & 63) == 0) { red[(tid >> 6) * 2] = s; red[(tid >> 6) * 2 + 1] = ss; }
    __syncthreads();
    s = red[0] + red[2] + red[4] + red[6];
    ss = red[1] + red[3] + red[5] + red[7];
    float mu = s * (1.f / D_);
    float var = (ss - (float)D_ * mu * mu) * (1.f / (D_ - 1));
    float rstd = rsqrtf(var + 1e-4f);
    #pragma unroll
    for (int i = 0; i < 4; ++i) {
        int d = tid + i * 256;
        out[(size_t)row * D_ + d] = f2bf((v[i] - mu) * rstd * w[d] + b[d]);
    }
}

// ---------------------------------------------------------------- gather + residual + LN2
__global__ __launch_bounds__(256) void resid_ln2_kernel(
    const float* __restrict__ x, const float* __restrict__ attn,
    const float* __restrict__ wsum, const float* __restrict__ w,
    const float* __restrict__ b, float* __restrict__ x1, ushort_t* __restrict__ out) {
    int row = blockIdx.x;           // row = bb*S + s
    int bb = row >> 11, sidx = row & 2047;
    int tid = threadIdx.x;
    float v[4], s = 0.f, ss = 0.f;
    #pragma unroll
    for (int i = 0; i < 4; ++i) {
        int d = tid + i * 256;
        int n = d >> 6;
        int sp = ((d & 63) << 5) + (sidx >> 6);
        int h = sidx & 63;
        float a = attn[(((size_t)bb * NH_ + n) * S_ + sp) * HD_ + h];
        float val = x[(size_t)row * D_ + d] + wsum[d] * a;
        x1[(size_t)row * D_ + d] = val;
        v[i] = val; s += val; ss += val * val;
    }
    #pragma unroll
    for (int off = 32; off >= 1; off >>= 1) { s += __shfl_xor(s, off); ss += __shfl_xor(ss, off); }
    __shared__ float red[8];
    if ((tid & 63) == 0) { red[(tid >> 6) * 2] = s; red[(tid >> 6) * 2 + 1] = ss; }
    __syncthreads();
    s = red[0] + red[2] + red[4] + red[6];
    ss = red[1] + red[3] + red[5] + red[7];
    float mu = s * (1.f / D_);
    float var = (ss - (float)D_ * mu * mu) * (1.f / (D_ - 1));
    float rstd = rsqrtf(var + 1e-4f);
    #pragma unroll
    for (int i = 0; i < 4; ++i) {
        int d = tid + i * 256;
        out[(size_t)row * D_ + d] = f2bf((v[i] - mu) * rstd * w[d] + b[d]);
    }
}

// ---------------------------------------------------------------- GEMM: C[M][N] = A[M][K] * BT[N][K]^T
// EPI 0: scatter to qkv[b][n][s][192] (bf16).  EPI 1: gelu(c+bias) -> bf16.  EPI 2: c+bias+resid -> f32.
template <int EPI>
__global__ __launch_bounds__(256) void gemm_bt(
    const ushort_t* __restrict__ A, const ushort_t* __restrict__ BT,
    int M, int N, int K, const float* __restrict__ bias,
    const float* __restrict__ resid, void* __restrict__ outp) {
    __shared__ __align__(16) ushort_t As[128 * 72];
    __shared__ __align__(16) ushort_t Bs[128 * 72];
    const int tid = threadIdx.x;
    const int lane = tid & 63, wave = tid >> 6;
    const int ln15 = lane & 15, qd = lane >> 4;
    const int wm = wave >> 1, wn = wave & 1;
    const int bm = blockIdx.y, bn = blockIdx.x;

    floatx4 acc[4][4];
    #pragma unroll
    for (int i = 0; i < 4; ++i)
        #pragma unroll
        for (int j = 0; j < 4; ++j) acc[i][j] = (floatx4){0.f, 0.f, 0.f, 0.f};

    for (int k0 = 0; k0 < K; k0 += 64) {
        __syncthreads();
        #pragma unroll
        for (int l = 0; l < 4; ++l) {
            int idx = tid + l * 256;
            int row = idx >> 3, c = idx & 7;
            uint4 va = *(const uint4*)(A + (size_t)(bm * 128 + row) * K + k0 + c * 8);
            *(uint4*)(&As[row * 72 + c * 8]) = va;
            uint4 vb = *(const uint4*)(BT + (size_t)(bn * 128 + row) * K + k0 + c * 8);
            *(uint4*)(&Bs[row * 72 + c * 8]) = vb;
        }
        __syncthreads();
        #pragma unroll
        for (int ks = 0; ks < 2; ++ks) {
            short8 a[4], b[4];
            #pragma unroll
            for (int mt = 0; mt < 4; ++mt)
                a[mt] = *(const short8*)&As[(wm * 64 + mt * 16 + ln15) * 72 + ks * 32 + qd * 8];
            #pragma unroll
            for (int nt = 0; nt < 4; ++nt)
                b[nt] = *(const short8*)&Bs[(wn * 64 + nt * 16 + ln15) * 72 + ks * 32 + qd * 8];
            #pragma unroll
            for (int mt = 0; mt < 4; ++mt)
                #pragma unroll
                for (int nt = 0; nt < 4; ++nt)
                    acc[mt][nt] = __builtin_amdgcn_mfma_f32_16x16x32_bf16(a[mt], b[nt], acc[mt][nt], 0, 0, 0);
        }
    }

    const int row0 = bm * 128 + wm * 64, col0 = bn * 128 + wn * 64;
    #pragma unroll
    for (int mt = 0; mt < 4; ++mt)
        #pragma unroll
        for (int nt = 0; nt < 4; ++nt)
            #pragma unroll
            for (int r = 0; r < 4; ++r) {
                int row = row0 + mt * 16 + qd * 4 + r;
                int col = col0 + nt * 16 + ln15;
                float v = acc[mt][nt][r];
                if (EPI == 0) {
                    int bb = row >> 11, sidx = row & 2047;
                    unsigned uc = (unsigned)col;
                    unsigned hn = uc / 192u;
                    unsigned j = uc - hn * 192u;
                    ((ushort_t*)outp)[(((size_t)bb * NH_ + hn) * S_ + sidx) * 192 + j] = f2bf(v);
                } else if (EPI == 1) {
                    v += bias[col];
                    float g = 0.5f * v * (1.0f + erff(v * 0.70710678118654752f));
                    ((ushort_t*)outp)[(size_t)row * N + col] = f2bf(g);
                } else {
                    v += bias[col] + resid[(size_t)row * N + col];
                    ((float*)outp)[(size_t)row * N + col] = v;
                }
            }
}

// ---------------------------------------------------------------- flash attention (causal), 64-row Q tiles
__global__ __launch_bounds__(256) void attn_kernel(const ushort_t* __restrict__ qkv,
                                                   const ushort_t* __restrict__ vT,
                                                   float* __restrict__ attn_out) {
    __shared__ __align__(16) ushort_t Qs[64 * 72];
    __shared__ __align__(16) ushort_t Ks[64 * 72];
    __shared__ __align__(16) ushort_t Vs[64 * 72];   // V^T tile: [hd][key]
    __shared__ __align__(16) ushort_t Ps[64 * 72];
    const int tid = threadIdx.x, lane = tid & 63, w = tid >> 6;
    const int ln15 = lane & 15, qd = lane >> 4;
    const int qt = blockIdx.x;
    const int bh = blockIdx.z * NH_ + blockIdx.y;
    const size_t qbase = (size_t)bh * S_ * 192;

    #pragma unroll
    for (int l = 0; l < 2; ++l) {
        int idx = tid + l * 256;
        int row = idx >> 3, c = idx & 7;
        *(uint4*)&Qs[row * 72 + c * 8] = *(const uint4*)(qkv + qbase + (size_t)(qt * 64 + row) * 192 + c * 8);
    }
    float mst[4], lst[4];
    floatx4 oacc[4];
    #pragma unroll
    for (int r = 0; r < 4; ++r) { mst[r] = -1e30f; lst[r] = 0.f; }
    #pragma unroll
    for (int nt = 0; nt < 4; ++nt) oacc[nt] = (floatx4){0.f, 0.f, 0.f, 0.f};

    for (int kt = 0; kt <= qt; ++kt) {
        __syncthreads();
        #pragma unroll
        for (int l = 0; l < 2; ++l) {
            int idx = tid + l * 256;
            int row = idx >> 3, c = idx & 7;
            *(uint4*)&Ks[row * 72 + c * 8] =
                *(const uint4*)(qkv + qbase + (size_t)(kt * 64 + row) * 192 + 64 + c * 8);
            *(uint4*)&Vs[row * 72 + c * 8] =
                *(const uint4*)(vT + ((size_t)bh * HD_ + row) * S_ + kt * 64 + c * 8);
        }
        __syncthreads();

        floatx4 sacc[4];
        #pragma unroll
        for (int nt = 0; nt < 4; ++nt) sacc[nt] = (floatx4){0.f, 0.f, 0.f, 0.f};
        #pragma unroll
        for (int ks = 0; ks < 2; ++ks) {
            short8 aq = *(const short8*)&Qs[(w * 16 + ln15) * 72 + ks * 32 + qd * 8];
            #pragma unroll
            for (int nt = 0; nt < 4; ++nt) {
                short8 bk = *(const short8*)&Ks[(nt * 16 + ln15) * 72 + ks * 32 + qd * 8];
                sacc[nt] = __builtin_amdgcn_mfma_f32_16x16x32_bf16(aq, bk, sacc[nt], 0, 0, 0);
            }
        }
        const bool diag = (kt == qt);
        float rmax[4] = {-1e30f, -1e30f, -1e30f, -1e30f};
        #pragma unroll
        for (int nt = 0; nt < 4; ++nt)
            #pragma unroll
            for (int r = 0; r < 4; ++r) {
                float v = sacc[nt][r] * 0.125f;
                if (diag && (nt * 16 + ln15 > w * 16 + qd * 4 + r)) v = -1e30f;
                sacc[nt][r] = v;
                rmax[r] = fmaxf(rmax[r], v);
            }
        #pragma unroll
        for (int r = 0; r < 4; ++r) {
            #pragma unroll
            for (int off = 8; off >= 1; off >>= 1) rmax[r] = fmaxf(rmax[r], __shfl_xor(rmax[r], off, 16));
        }
        float alpha[4], rsum[4];
        #pragma unroll
        for (int r = 0; r < 4; ++r) {
            float mn = fmaxf(mst[r], rmax[r]);
            alpha[r] = __expf(mst[r] - mn);
            mst[r] = mn;
            rsum[r] = 0.f;
        }
        #pragma unroll
        for (int nt = 0; nt < 4; ++nt)
            #pragma unroll
            for (int r = 0; r < 4; ++r) {
                float p = __expf(sacc[nt][r] - mst[r]);
                rsum[r] += p;
                Ps[(w * 16 + qd * 4 + r) * 72 + nt * 16 + ln15] = f2bf(p);
            }
        #pragma unroll
        for (int r = 0; r < 4; ++r) {
            #pragma unroll
            for (int off = 8; off >= 1; off >>= 1) rsum[r] += __shfl_xor(rsum[r], off, 16);
            lst[r] = lst[r] * alpha[r] + rsum[r];
        }
        #pragma unroll
        for (int nt = 0; nt < 4; ++nt)
            #pragma unroll
            for (int r = 0; r < 4; ++r) oacc[nt][r] *= alpha[r];
        __syncthreads();   // Ps visibility (wave-private region, but keep ordering safe)
        #pragma unroll
        for (int ks = 0; ks < 2; ++ks) {
            short8 ap = *(const short8*)&Ps[(w * 16 + ln15) * 72 + ks * 32 + qd * 8];
            #pragma unroll
            for (int nt = 0; nt < 4; ++nt) {
                short8 bv = *(const short8*)&Vs[(nt * 16 + ln15) * 72 + ks * 32 + qd * 8];
                oacc[nt] = __builtin_amdgcn_mfma_f32_16x16x32_bf16(ap, bv, oacc[nt], 0, 0, 0);
            }
        }
    }
    #pragma unroll
    for (int nt = 0; nt < 4; ++nt)
        #pragma unroll
        for (int r = 0; r < 4; ++r) {
            int q = qt * 64 + w * 16 + qd * 4 + r;
            attn_out[((size_t)bh * S_ + q) * HD_ + nt * 16 + ln15] = oacc[nt][r] / lst[r];
        }
}

// ---------------------------------------------------------------- launch
extern "C" void kernel_launch(void* const* d_in, const int* in_sizes, int n_in,
                              void* d_out, int out_size, void* d_ws, size_t ws_size,
                              hipStream_t stream) {
    const float* x = (const float*)d_in[0];
    const float* W_qkv = (const float*)d_in[1];
    const float* W_out = (const float*)d_in[2];
    const float* ln1_w = (const float*)d_in[3];
    const float* ln1_b = (const float*)d_in[4];
    const float* ln2_w = (const float*)d_in[5];
    const float* ln2_b = (const float*)d_in[6];
    const float* W1 = (const float*)d_in[7];
    const float* b1 = (const float*)d_in[8];
    const float* W2 = (const float*)d_in[9];
    const float* b2 = (const float*)d_in[10];

    char* ws = (char*)d_ws;
    size_t off = 0;
    auto alloc = [&](size_t bytes) { char* p = ws + off; off += (bytes + 255) & ~(size_t)255; return p; };
    ushort_t* ln1_out = (ushort_t*)alloc((size_t)B_ * S_ * D_ * 2);          // 8 MiB
    ushort_t* WqkvT  = (ushort_t*)alloc((size_t)NH_ * 192 * D_ * 2);         // 6 MiB
    ushort_t* qkv    = (ushort_t*)alloc((size_t)B_ * NH_ * S_ * 192 * 2);    // 24 MiB
    ushort_t* vT     = (ushort_t*)alloc((size_t)B_ * NH_ * HD_ * S_ * 2);    // 8 MiB
    float*    attn_o = (float*)alloc((size_t)B_ * NH_ * S_ * HD_ * 4);       // 16 MiB
    float*    x1     = (float*)alloc((size_t)B_ * S_ * D_ * 4);              // 16 MiB
    ushort_t* ln2_out = (ushort_t*)alloc((size_t)B_ * S_ * D_ * 2);          // 8 MiB
    ushort_t* W1T    = (ushort_t*)alloc((size_t)M_ * D_ * 2);                // 8 MiB
    ushort_t* hbuf   = (ushort_t*)alloc((size_t)B_ * S_ * M_ * 2);           // 32 MiB
    ushort_t* W2T    = (ushort_t*)alloc((size_t)D_ * M_ * 2);                // 8 MiB
    float*    wsum   = (float*)alloc(D_ * 4);

    dim3 tb(32, 8);
    // W_qkv [16][1024][192] -> WqkvT [16*192][1024]
    transpose_to_bf16<float><<<dim3(192 / 32, D_ / 32, NH_), tb, 0, stream>>>(
        W_qkv, WqkvT, D_, 192, (long)D_ * 192, (long)192 * D_, 192, D_);
    // W1 [1024][4096] -> W1T [4096][1024]
    transpose_to_bf16<float><<<dim3(M_ / 32, D_ / 32, 1), tb, 0, stream>>>(
        W1, W1T, D_, M_, 0, 0, M_, D_);
    // W2 [4096][1024] -> W2T [1024][4096]
    transpose_to_bf16<float><<<dim3(D_ / 32, M_ / 32, 1), tb, 0, stream>>>(
        W2, W2T, M_, D_, 0, 0, D_, M_);
    wsum_kernel<<<dim3(D_ / 32), 256, 0, stream>>>(W_out, wsum);
    ln1_kernel<<<dim3(B_ * S_), 256, 0, stream>>>(x, ln1_w, ln1_b, ln1_out);
    // QKV GEMM: [4096 x 1024] x [3072 x 1024]^T -> qkv scatter
    gemm_bt<0><<<dim3(3072 / 128, (B_ * S_) / 128), 256, 0, stream>>>(
        ln1_out, WqkvT, B_ * S_, 3072, D_, nullptr, nullptr, qkv);
    // v slice of qkv -> vT [bh][hd][s]
    transpose_to_bf16<ushort_t><<<dim3(HD_ / 32, S_ / 32, B_ * NH_), tb, 0, stream>>>(
        qkv + 128, vT, S_, HD_, (long)S_ * 192, (long)HD_ * S_, 192, S_);
    attn_kernel<<<dim3(S_ / 64, NH_, B_), 256, 0, stream>>>(qkv, vT, attn_o);
    resid_ln2_kernel<<<dim3(B_ * S_), 256, 0, stream>>>(x, attn_o, wsum, ln2_w, ln2_b, x1, ln2_out);
    // MLP1: [4096 x 1024] x [4096 x 1024]^T -> gelu -> h
    gemm_bt<1><<<dim3(M_ / 128, (B_ * S_) / 128), 256, 0, stream>>>(
        ln2_out, W1T, B_ * S_, M_, D_, b1, nullptr, hbuf);
    // MLP2: [4096 x 4096] x [1024 x 4096]^T + b2 + x1 -> d_out (fp32)
    gemm_bt<2><<<dim3(D_ / 128, (B_ * S_) / 128), 256, 0, stream>>>(
        hbuf, W2T, B_ * S_, D_, M_, b2, x1, (float*)d_out);
}